// Round 4
// baseline (273.204 us; speedup 1.0000x reference)
//
#include <hip/hip_runtime.h>
#include <hip/hip_bf16.h>

#define T_TOK 2048
#define H_DIM 1024
#define E_N   8
#define I_DIM 2048

#define NT_MAX 40         // sum ceil(cnt_e/128) <= 4096/128 + 7 = 39
#define MAX_SLOTS 5120    // 40 tiles * 128 rows

typedef unsigned short u16;
typedef unsigned int   u32;
typedef __bf16 bf16_t;
typedef bf16_t bf16x8 __attribute__((ext_vector_type(8)));
typedef u16    u16x8  __attribute__((ext_vector_type(8)));
typedef float  f32x4  __attribute__((ext_vector_type(4)));

#define MFMA __builtin_amdgcn_mfma_f32_16x16x32_bf16

__device__ __forceinline__ u16 bfbits(float f) {
    bf16_t b = (bf16_t)f;
    return __builtin_bit_cast(u16, b);
}

// swizzled LDS offset (u16 elems) for transposed B tile: row n (0..63), k-block kb (0..7)
// row stride 72 u16 (=144B) itself rotates bank groups by 4 dwords/row; XOR adds depth.
__device__ __forceinline__ int bt_off(int n, int kb) {
    return n * 72 + ((kb ^ ((n >> 2) & 7)) << 3);
}

// ---------------- router: logits -> top2 -> normalized weights -> expert lists
// (also converts this token's x row to bf16)
__global__ __launch_bounds__(64) void router_k(
    const float* __restrict__ x, const float* __restrict__ rw,
    int* __restrict__ cnt, int* __restrict__ tok, float* __restrict__ wts,
    u16* __restrict__ xbf)
{
    int t = blockIdx.x;
    int lane = threadIdx.x;
    const float* xr = x + (size_t)t * H_DIM;
    u16* xbr = xbf + (size_t)t * H_DIM;

    float acc[E_N];
#pragma unroll
    for (int e = 0; e < E_N; e++) acc[e] = 0.f;
    for (int j = 0; j < H_DIM / 64; j++) {
        float xv = xr[lane + 64 * j];
        xbr[lane + 64 * j] = bfbits(xv);
#pragma unroll
        for (int e = 0; e < E_N; e++)
            acc[e] += xv * rw[e * H_DIM + lane + 64 * j];
    }
#pragma unroll
    for (int e = 0; e < E_N; e++) {
        float v = acc[e];
        for (int off = 32; off; off >>= 1) v += __shfl_xor(v, off);
        acc[e] = v;
    }
    if (lane == 0) {
        int i0 = 0; float m0 = acc[0];
#pragma unroll
        for (int e = 1; e < E_N; e++) if (acc[e] > m0) { m0 = acc[e]; i0 = e; }
        int i1 = -1; float m1 = -INFINITY;
#pragma unroll
        for (int e = 0; e < E_N; e++) if (e != i0 && acc[e] > m1) { m1 = acc[e]; i1 = e; }
        float w0 = 1.f / (1.f + expf(m1 - m0));
        float w1 = 1.f - w0;
        int p0 = atomicAdd(&cnt[i0], 1);
        tok[i0 * T_TOK + p0] = t; wts[i0 * T_TOK + p0] = w0;
        int p1 = atomicAdd(&cnt[i1], 1);
        tok[i1 * T_TOK + p1] = t; wts[i1 * T_TOK + p1] = w1;
    }
}

// ---------------- prefix + padded tile map (BM=128)
__global__ void prefix_k(const int* __restrict__ cnt, int* __restrict__ offs_pad,
                         int* __restrict__ tile_e, int* __restrict__ tile_row0,
                         int* __restrict__ ntiles)
{
    if (threadIdx.x == 0) {
        int s = 0, nt = 0;
        for (int e = 0; e < E_N; e++) {
            offs_pad[e] = s;
            int c = cnt[e];
            int t = (c + 127) >> 7;
            for (int i = 0; i < t; i++) { tile_e[nt] = e; tile_row0[nt] = i * 128; nt++; }
            s += t * 128;
        }
        offs_pad[E_N] = s;
        *ntiles = nt;
    }
}

// ---------------- gate/up grouped GEMM: act[slot][i] = silu(x@wg)*(x@wu)
// tile 128x64, BK=64, 4 waves (2Mx2N), wave tile 64x32 per matrix, dbuf LDS.
// threads 0-127 stage gate, 128-255 stage up (8 float4 each, one matrix).
__global__ __launch_bounds__(256, 3) void gateup_k(
    const u16* __restrict__ xbf, const float* __restrict__ wg, const float* __restrict__ wu,
    const int* __restrict__ cnt, const int* __restrict__ offs_pad,
    const int* __restrict__ tile_e, const int* __restrict__ tile_row0,
    const int* __restrict__ ntiles, const int* __restrict__ tok,
    u16* __restrict__ act)
{
    // chunked XCD swizzle: consecutive logicals (tb fastest) land on one XCD
    int q = gridDim.x >> 3;
    int phys = blockIdx.x;
    int logical = (phys & 7) * q + (phys >> 3);
    int tb = logical % NT_MAX;
    int n0 = (logical / NT_MAX) * 64;
    if (tb >= *ntiles) return;
    int e = tile_e[tb], row0 = tile_row0[tb];
    int cntE = cnt[e];
    int slot0 = offs_pad[e] + row0;

    __shared__ u16 BT[2][2][64 * 72];   // [buf][mat][n][k] transposed+swizzled, 36 KB

    int tid = threadIdx.x;
    int lane = tid & 63, wid = tid >> 6;
    int wm = wid >> 1, wn = wid & 1;
    int l15 = lane & 15, lg = lane >> 4;

    // A row pointers (gathered tokens), clamped
    const u16* arow[4];
#pragma unroll
    for (int mf = 0; mf < 4; mf++) {
        int rr = row0 + wm * 64 + mf * 16 + l15;
        int rc = rr < cntE ? rr : cntE - 1;
        arow[mf] = xbf + (size_t)tok[e * T_TOK + rc] * H_DIM;
    }

    // staging role: one matrix per half-block
    int mat  = tid >> 7;           // 0: gate, 1: up
    int tid7 = tid & 127;
    int kb   = tid7 >> 4;          // k-chunk (8 rows)
    int sn   = (tid7 & 15) * 4;    // 4 cols

    const float* wptr = (mat ? wu : wg) + ((size_t)e * H_DIM + kb * 8) * I_DIM + n0 + sn;

    float4 v[8];
#pragma unroll
    for (int i = 0; i < 8; i++)
        v[i] = *reinterpret_cast<const float4*>(wptr + (size_t)i * I_DIM);

    f32x4 accg[4][2], accu[4][2];
#pragma unroll
    for (int a = 0; a < 4; a++)
#pragma unroll
        for (int b = 0; b < 2; b++) { accg[a][b] = (f32x4)0.f; accu[a][b] = (f32x4)0.f; }

#pragma unroll 2
    for (int k0 = 0; k0 < H_DIM; k0 += 64) {
        int buf = (k0 >> 6) & 1;
        // convert staged regs (data for k0) -> LDS (transposed)
#pragma unroll
        for (int c = 0; c < 4; c++) {
            u16x8 p;
#pragma unroll
            for (int i = 0; i < 8; i++) {
                float f = (c == 0) ? v[i].x : (c == 1) ? v[i].y : (c == 2) ? v[i].z : v[i].w;
                p[i] = bfbits(f);
            }
            *reinterpret_cast<u16x8*>(&BT[buf][mat][bt_off(sn + c, kb)]) = p;
        }
        // issue next tile's loads (overlap with this tile's MFMA)
        if (k0 + 64 < H_DIM) {
#pragma unroll
            for (int i = 0; i < 8; i++)
                v[i] = *reinterpret_cast<const float4*>(wptr + (size_t)(k0 + 64 + i) * I_DIM);
        }
        __syncthreads();

#pragma unroll
        for (int ks = 0; ks < 2; ks++) {
            bf16x8 af[4];
#pragma unroll
            for (int mf = 0; mf < 4; mf++)
                af[mf] = *reinterpret_cast<const bf16x8*>(arow[mf] + k0 + ks * 32 + lg * 8);
            int kbr = ks * 4 + lg;
#pragma unroll
            for (int nf = 0; nf < 2; nf++) {
                int c = wn * 32 + nf * 16 + l15;
                bf16x8 bg = *reinterpret_cast<const bf16x8*>(&BT[buf][0][bt_off(c, kbr)]);
                bf16x8 bu = *reinterpret_cast<const bf16x8*>(&BT[buf][1][bt_off(c, kbr)]);
#pragma unroll
                for (int mf = 0; mf < 4; mf++) {
                    accg[mf][nf] = MFMA(af[mf], bg, accg[mf][nf], 0, 0, 0);
                    accu[mf][nf] = MFMA(af[mf], bu, accu[mf][nf], 0, 0, 0);
                }
            }
        }
        // no trailing barrier: dbuf + next iter's barrier order buffer reuse
    }

    // epilogue: silu(g)*u -> bf16; padded rows -> 0 (down_k reads them)
#pragma unroll
    for (int mf = 0; mf < 4; mf++)
#pragma unroll
        for (int j = 0; j < 4; j++) {
            int rl = wm * 64 + mf * 16 + lg * 4 + j;
            bool valid = (row0 + rl) < cntE;
            size_t base = (size_t)(slot0 + rl) * I_DIM + n0;
#pragma unroll
            for (int nf = 0; nf < 2; nf++) {
                float g = accg[mf][nf][j];
                float u = accu[mf][nf][j];
                float a = valid ? (g / (1.f + expf(-g))) * u : 0.f;
                act[base + wn * 32 + nf * 16 + l15] = bfbits(a);
            }
        }
}

// ---------------- down grouped GEMM: out[t] += w * (act @ w_down[e])
// tile 128x64, K split in 2 halves of 1024, dbuf LDS 18 KB.
__global__ __launch_bounds__(256, 4) void down_k(
    const u16* __restrict__ act, const float* __restrict__ wd,
    const int* __restrict__ cnt, const int* __restrict__ offs_pad,
    const int* __restrict__ tile_e, const int* __restrict__ tile_row0,
    const int* __restrict__ ntiles, const int* __restrict__ tok,
    const float* __restrict__ wts, float* __restrict__ out)
{
    int q = gridDim.x >> 3;
    int phys = blockIdx.x;
    int logical = (phys & 7) * q + (phys >> 3);
    int tb = logical % NT_MAX;
    int rest = logical / NT_MAX;
    int h0 = (rest & 15) * 64;
    int kh = rest >> 4;                 // K half: 0 or 1
    if (tb >= *ntiles) return;
    int e = tile_e[tb], row0 = tile_row0[tb];
    int cntE = cnt[e];
    int slot0 = offs_pad[e] + row0;

    __shared__ u16 BT[2][64 * 72];

    int tid = threadIdx.x;
    int lane = tid & 63, wid = tid >> 6;
    int wm = wid >> 1, wn = wid & 1;
    int l15 = lane & 15, lg = lane >> 4;

    const u16* arow[4];
#pragma unroll
    for (int mf = 0; mf < 4; mf++)
        arow[mf] = act + (size_t)(slot0 + wm * 64 + mf * 16 + l15) * I_DIM + kh * 1024;

    int kb = tid >> 5;                  // k-chunk (8 rows)
    int sn = (tid & 31) * 2;            // 2 cols

    const float* dptr = wd + ((size_t)e * I_DIM + kh * 1024 + kb * 8) * H_DIM + h0 + sn;

    float2 v[8];
#pragma unroll
    for (int i = 0; i < 8; i++)
        v[i] = *reinterpret_cast<const float2*>(dptr + (size_t)i * H_DIM);

    f32x4 acc[4][2];
#pragma unroll
    for (int a = 0; a < 4; a++)
#pragma unroll
        for (int b = 0; b < 2; b++) acc[a][b] = (f32x4)0.f;

#pragma unroll 2
    for (int k0 = 0; k0 < 1024; k0 += 64) {
        int buf = (k0 >> 6) & 1;
#pragma unroll
        for (int c = 0; c < 2; c++) {
            u16x8 p;
#pragma unroll
            for (int i = 0; i < 8; i++)
                p[i] = bfbits(c ? v[i].y : v[i].x);
            *reinterpret_cast<u16x8*>(&BT[buf][bt_off(sn + c, kb)]) = p;
        }
        if (k0 + 64 < 1024) {
#pragma unroll
            for (int i = 0; i < 8; i++)
                v[i] = *reinterpret_cast<const float2*>(dptr + (size_t)(k0 + 64 + i) * H_DIM);
        }
        __syncthreads();

#pragma unroll
        for (int ks = 0; ks < 2; ks++) {
            bf16x8 af[4];
#pragma unroll
            for (int mf = 0; mf < 4; mf++)
                af[mf] = *reinterpret_cast<const bf16x8*>(arow[mf] + k0 + ks * 32 + lg * 8);
            int kbr = ks * 4 + lg;
#pragma unroll
            for (int nf = 0; nf < 2; nf++) {
                int c = wn * 32 + nf * 16 + l15;
                bf16x8 bfr = *reinterpret_cast<const bf16x8*>(&BT[buf][bt_off(c, kbr)]);
#pragma unroll
                for (int mf = 0; mf < 4; mf++)
                    acc[mf][nf] = MFMA(af[mf], bfr, acc[mf][nf], 0, 0, 0);
            }
        }
    }

#pragma unroll
    for (int mf = 0; mf < 4; mf++)
#pragma unroll
        for (int j = 0; j < 4; j++) {
            int rl = wm * 64 + mf * 16 + lg * 4 + j;
            int gr = row0 + rl;
            if (gr < cntE) {
                float w = wts[e * T_TOK + gr];
                int t   = tok[e * T_TOK + gr];
                size_t base = (size_t)t * H_DIM + h0;
#pragma unroll
                for (int nf = 0; nf < 2; nf++)
                    atomicAdd(&out[base + wn * 32 + nf * 16 + l15], acc[mf][nf][j] * w);
            }
        }
}

extern "C" void kernel_launch(void* const* d_in, const int* in_sizes, int n_in,
                              void* d_out, int out_size, void* d_ws, size_t ws_size,
                              hipStream_t stream)
{
    const float* x  = (const float*)d_in[0];
    const float* rw = (const float*)d_in[1];
    const float* wg = (const float*)d_in[2];
    const float* wu = (const float*)d_in[3];
    const float* wd = (const float*)d_in[4];
    float* out = (float*)d_out;

    char* ws = (char*)d_ws;
    int*   cnt       = (int*)(ws);                 // 8 ints
    int*   ntiles    = (int*)(ws + 32);
    int*   offs_pad  = (int*)(ws + 64);            // 9 ints
    int*   tile_e    = (int*)(ws + 256);           // NT_MAX ints
    int*   tile_row0 = (int*)(ws + 512);           // NT_MAX ints
    int*   tok       = (int*)(ws + 64 * 1024);     // E*T ints (64 KB)
    float* wts       = (float*)(ws + 128 * 1024);  // 64 KB
    u16*   xbf       = (u16*)(ws + 256 * 1024);    // 4 MB
    u16*   act       = (u16*)(ws + 4608 * 1024);   // 5120*2048*2 = 21 MB

    size_t need = 4608ull * 1024 + (size_t)MAX_SLOTS * I_DIM * 2;
    if (ws_size < need) return;

    hipMemsetAsync(cnt, 0, 32, stream);
    hipMemsetAsync(out, 0, (size_t)T_TOK * H_DIM * sizeof(float), stream);

    router_k<<<T_TOK, 64, 0, stream>>>(x, rw, cnt, tok, wts, xbf);
    prefix_k<<<1, 64, 0, stream>>>(cnt, offs_pad, tile_e, tile_row0, ntiles);
    gateup_k<<<NT_MAX * (I_DIM / 64), 256, 0, stream>>>(
        xbf, wg, wu, cnt, offs_pad, tile_e, tile_row0, ntiles, tok, act);
    down_k<<<NT_MAX * (H_DIM / 64) * 2, 256, 0, stream>>>(
        act, wd, cnt, offs_pad, tile_e, tile_row0, ntiles, tok, wts, out);
}